// Round 4
// baseline (359.023 us; speedup 1.0000x reference)
//
#include <hip/hip_runtime.h>
#include <hip/hip_fp16.h>

#define BATCH 4096
#define EPS 1e-5f

typedef __half h16;

union H8 { float4 f4; h16 h[8]; };
union H4 { float2 f2; h16 h[4]; };
union H2U { float f; __half2 h2; unsigned int u; };

__device__ __forceinline__ float tanh_fast(float x){
  float e = __expf(2.0f*x);
  return 1.0f - 2.0f*__builtin_amdgcn_rcpf(e + 1.0f);
}

__device__ __forceinline__ float wred(float v){
  #pragma unroll
  for (int off=32; off; off>>=1) v += __shfl_xor(v, off);
  return v;
}

// ---------------- transpose: ms[4096][6000] f32 -> msT[6000][4096] f16 ----------------
__global__ __launch_bounds__(256) void k_transpose(const float* __restrict__ ms, h16* __restrict__ msT){
  __shared__ float tile[64][65];
  int tc = blockIdx.x * 64;
  int tb = blockIdx.y * 64;
  int tx = threadIdx.x & 63;
  int ty = threadIdx.x >> 6;
  #pragma unroll
  for (int k=0;k<16;++k){
    int r = ty + k*4;
    int c = tc + tx;
    if (c < 6000) tile[r][tx] = ms[(size_t)(tb + r)*6000 + c];
  }
  __syncthreads();
  #pragma unroll
  for (int k=0;k<16;++k){
    int r = ty + k*4;
    int c = tc + r;
    if (c < 6000) msT[(size_t)c*BATCH + tb + tx] = __float2half(tile[tx][r]);
  }
}

// ---------------- pass A: level-1 stats only ----------------
// grid (16 bc, 512 s), block 64; thread handles 4 batch elems
__global__ __launch_bounds__(64) void k_statsA(const h16* __restrict__ msT, const int* __restrict__ gidx,
    const float* __restrict__ W1, const float* __restrict__ b1, float* __restrict__ part1){
  const int s = blockIdx.y;
  const int bc = blockIdx.x;           // 16
  const int lane = threadIdx.x;
  const int b0 = bc*256 + lane*4;
  const float* Wp = W1 + s*320;
  float acc[20][4];
  #pragma unroll
  for (int o=0;o<20;++o){
    float bv = b1[s*20+o];
    acc[o][0]=bv; acc[o][1]=bv; acc[o][2]=bv; acc[o][3]=bv;
  }
  #pragma unroll 4
  for (int g=0; g<16; ++g){
    const int row = gidx[s*16+g]*BATCH;
    H4 u; u.f2 = *reinterpret_cast<const float2*>(msT + row + b0);
    float x0=__half2float(u.h[0]), x1=__half2float(u.h[1]);
    float x2=__half2float(u.h[2]), x3=__half2float(u.h[3]);
    #pragma unroll
    for (int o=0;o<20;++o){
      float wv = Wp[o*16+g];
      acc[o][0]=fmaf(x0,wv,acc[o][0]);
      acc[o][1]=fmaf(x1,wv,acc[o][1]);
      acc[o][2]=fmaf(x2,wv,acc[o][2]);
      acc[o][3]=fmaf(x3,wv,acc[o][3]);
    }
  }
  #pragma unroll
  for (int o=0;o<20;++o){
    float h0=tanh_fast(acc[o][0]), h1=tanh_fast(acc[o][1]);
    float h2=tanh_fast(acc[o][2]), h3=tanh_fast(acc[o][3]);
    float S = wred((h0+h1)+(h2+h3));
    float Q = wred((h0*h0+h1*h1)+(h2*h2+h3*h3));
    if (lane==0){
      part1[((s*20+o)*2  )*16 + bc] = S;
      part1[((s*20+o)*2+1)*16 + bc] = Q;
    }
  }
}

// ---------------- fold level-1 BN into W2 (transposed [i][j] layout) ----------------
__global__ __launch_bounds__(256) void k_fold2(const float* __restrict__ W, const float* __restrict__ bb,
    const float* __restrict__ g, const float* __restrict__ beta,
    const float* __restrict__ part, float* __restrict__ Wf, float* __restrict__ bf){
  const int p = blockIdx.x;
  const int tid = threadIdx.x;
  __shared__ float aL[160], cL[160];
  for (int t = tid; t < 160; t += 256){
    int ch = p*160 + t;
    float S=0.f, Q=0.f;
    for (int bc=0; bc<16; ++bc){ S += part[(ch*2)*16 + bc]; Q += part[(ch*2+1)*16 + bc]; }
    float mu  = S * (1.0f/BATCH);
    float var = Q * (1.0f/BATCH) - mu*mu;
    float a = g[ch] * rsqrtf(var + EPS);
    aL[t] = a;
    cL[t] = beta[ch] - a*mu;
  }
  __syncthreads();
  const int NW = 160*24;
  for (int e = tid; e < NW; e += 256){
    int j = e % 24, i = e / 24;
    Wf[p*NW + e] = W[p*NW + j*160 + i] * aL[i];
  }
  if (tid < 24){
    float sv = bb[p*24 + tid];
    for (int i=0;i<160;++i) sv = fmaf(W[p*NW + tid*160 + i], cL[i], sv);
    bf[p*24 + tid] = sv;
  }
}

// ---------------- pass B: recompute h1 + folded level-2 -> H2[p][b][24] + stats ----------------
// grid (64 bc, 64 p), block 256 = 4 waves; wave wv handles children {2wv, 2wv+1}; LDS combine
__global__ __launch_bounds__(256) void k_passB(const h16* __restrict__ msT, const int* __restrict__ gidx,
    const float* __restrict__ W1, const float* __restrict__ b1,
    const float* __restrict__ W2f, const float* __restrict__ b2f,
    h16* __restrict__ H2, float* __restrict__ part2){
  const int p = blockIdx.y;
  const int bc = blockIdx.x;           // 64
  const int tid = threadIdx.x;
  const int wv = tid >> 6;
  const int lane = tid & 63;
  const int b = bc*64 + lane;
  __shared__ float lacc[4][64][25];
  float acc[24];
  if (wv == 0){
    #pragma unroll
    for (int j=0;j<24;++j) acc[j] = b2f[p*24+j];
  } else {
    #pragma unroll
    for (int j=0;j<24;++j) acc[j] = 0.f;
  }
  #pragma unroll
  for (int cc=0; cc<2; ++cc){
    const int c2 = wv*2 + cc;
    const int s = p*8 + c2;
    const float* Wp = W1 + s*320;
    const float* bp = b1 + s*20;
    float x[16];
    #pragma unroll
    for (int g=0; g<16; ++g){
      const int row = gidx[s*16+g]*BATCH;
      x[g] = __half2float(msT[row + b]);
    }
    const float* w2 = W2f + p*3840 + c2*480;   // [i][j] layout
    #pragma unroll 4
    for (int o=0;o<20;++o){
      float h = bp[o];
      #pragma unroll
      for (int g=0; g<16; ++g) h = fmaf(x[g], Wp[o*16+g], h);
      h = tanh_fast(h);
      const float* wj = w2 + o*24;
      #pragma unroll
      for (int j=0;j<24;++j) acc[j] = fmaf(h, wj[j], acc[j]);
    }
  }
  #pragma unroll
  for (int j=0;j<24;++j) lacc[wv][lane][j] = acc[j];
  __syncthreads();
  #pragma unroll
  for (int k=0;k<6;++k){
    const int j = k*4 + wv;
    float v = (lacc[0][lane][j] + lacc[1][lane][j]) + (lacc[2][lane][j] + lacc[3][lane][j]);
    v = tanh_fast(v);
    H2[((size_t)p*BATCH + b)*24 + j] = __float2half(v);
    float S = wred(v);
    float Q = wred(v*v);
    if (lane==0){
      part2[((p*24+j)*2  )*64 + bc] = S;
      part2[((p*24+j)*2+1)*64 + bc] = Q;
    }
  }
}

// ---------------- pass C: inline-BN(level2) + level-3 -> H3[b][256] + stats ----------------
// grid (64 bc, 8 q), block 512 (8 waves x 4 outputs)
__global__ __launch_bounds__(512) void k_passC(const h16* __restrict__ H2, const float* __restrict__ part2,
    const float* __restrict__ g2, const float* __restrict__ beta2,
    const float* __restrict__ W3, const float* __restrict__ b3,
    h16* __restrict__ H3, float* __restrict__ part3){
  const int q = blockIdx.y;
  const int bc = blockIdx.x;           // 64
  const int tid = threadIdx.x;
  const int wv = tid >> 6;
  const int lane = tid & 63;
  __shared__ float aL[192], cL[192];
  for (int t = tid; t < 192; t += 512){
    int ch = q*192 + t;
    float S=0.f, Q=0.f;
    for (int c=0;c<64;++c){ S += part2[(ch*2)*64 + c]; Q += part2[(ch*2+1)*64 + c]; }
    float mu  = S * (1.0f/BATCH);
    float var = Q * (1.0f/BATCH) - mu*mu;
    float a = g2[ch] * rsqrtf(var + EPS);
    aL[t] = a; cL[t] = beta2[ch] - a*mu;
  }
  __syncthreads();
  const int b = bc*64 + lane;
  const int jb = wv*4;
  float acc[4];
  #pragma unroll
  for (int j=0;j<4;++j) acc[j] = b3[q*32 + jb + j];
  for (int c2=0;c2<8;++c2){
    const h16* src = H2 + ((size_t)(q*8+c2)*BATCH + b)*24;
    float xn[24];
    #pragma unroll
    for (int t=0;t<3;++t){
      H8 u; u.f4 = *reinterpret_cast<const float4*>(src + t*8);
      #pragma unroll
      for (int i=0;i<8;++i){
        int ci = c2*24 + t*8 + i;
        xn[t*8+i] = fmaf(aL[ci], __half2float(u.h[i]), cL[ci]);
      }
    }
    #pragma unroll
    for (int j=0;j<4;++j){
      const float* wr = W3 + q*6144 + (jb+j)*192 + c2*24;
      #pragma unroll
      for (int i=0;i<24;++i) acc[j] = fmaf(xn[i], wr[i], acc[j]);
    }
  }
  #pragma unroll
  for (int j=0;j<4;++j) acc[j] = tanh_fast(acc[j]);
  {
    h16* dst = H3 + (size_t)b*256 + q*32 + jb;
    H2U u0,u1;
    u0.h2 = __halves2half2(__float2half(acc[0]), __float2half(acc[1]));
    u1.h2 = __halves2half2(__float2half(acc[2]), __float2half(acc[3]));
    float2 v; v.x = u0.f; v.y = u1.f;
    *reinterpret_cast<float2*>(dst) = v;
  }
  #pragma unroll
  for (int j=0;j<4;++j){
    float S = wred(acc[j]);
    float Q = wred(acc[j]*acc[j]);
    if (lane==0){
      part3[((q*32+jb+j)*2  )*64 + bc] = S;
      part3[((q*32+jb+j)*2+1)*64 + bc] = Q;
    }
  }
}

// ---------------- pass D: inline-BN(level3) + root -> Hr f32 [b][64] + stats ----------------
// grid (64 bc, 8 jg), block 256 = 4 waves; wave wv handles channels [wv*64, wv*64+64); LDS combine
__global__ __launch_bounds__(256) void k_passD(const h16* __restrict__ H3, const float* __restrict__ part3,
    const float* __restrict__ g3, const float* __restrict__ beta3,
    const float* __restrict__ Wr, const float* __restrict__ br,
    float* __restrict__ Hr, float* __restrict__ partR){
  const int bc = blockIdx.x;           // 64
  const int jb = blockIdx.y * 8;       // 8 groups
  const int tid = threadIdx.x;
  const int wv = tid >> 6;
  const int lane = tid & 63;
  __shared__ float aL[256], cL[256];
  __shared__ float lacc[4][64][9];
  {
    float S=0.f, Q=0.f;
    for (int c=0;c<64;++c){ S += part3[(tid*2)*64 + c]; Q += part3[(tid*2+1)*64 + c]; }
    float mu  = S * (1.0f/BATCH);
    float var = Q * (1.0f/BATCH) - mu*mu;
    float a = g3[tid] * rsqrtf(var + EPS);
    aL[tid] = a; cL[tid] = beta3[tid] - a*mu;
  }
  __syncthreads();
  const int b = bc*64 + lane;
  float acc[8];
  #pragma unroll
  for (int j=0;j<8;++j) acc[j] = 0.f;
  const h16* src = H3 + (size_t)b*256 + wv*64;
  #pragma unroll
  for (int kk=0; kk<8; ++kk){
    const int sl = wv*8 + kk;
    H8 u; u.f4 = *reinterpret_cast<const float4*>(src + kk*8);
    float xn[8];
    #pragma unroll
    for (int i=0;i<8;++i){
      int ci = sl*8+i;
      xn[i] = fmaf(aL[ci], __half2float(u.h[i]), cL[ci]);
    }
    #pragma unroll
    for (int j=0;j<8;++j){
      const float* wr = Wr + (jb+j)*256 + sl*8;
      #pragma unroll
      for (int i=0;i<8;++i) acc[j] = fmaf(xn[i], wr[i], acc[j]);
    }
  }
  #pragma unroll
  for (int j=0;j<8;++j) lacc[wv][lane][j] = acc[j];
  __syncthreads();
  #pragma unroll
  for (int k=0;k<2;++k){
    const int j = k*4 + wv;
    float v = br[jb+j] + (lacc[0][lane][j] + lacc[1][lane][j]) + (lacc[2][lane][j] + lacc[3][lane][j]);
    v = tanh_fast(v);
    Hr[(size_t)b*64 + jb + j] = v;
    float S = wred(v);
    float Q = wred(v*v);
    if (lane==0){
      partR[((jb+j)*2  )*64 + bc] = S;
      partR[((jb+j)*2+1)*64 + bc] = Q;
    }
  }
}

// ---------------- final BN on root output ----------------
__global__ __launch_bounds__(256) void k_final(const float* __restrict__ Hr, const float* __restrict__ partR,
    const float* __restrict__ gr, const float* __restrict__ betar, float* __restrict__ out){
  __shared__ float aL[64], cL[64];
  const int tid = threadIdx.x;
  if (tid < 64){
    float S=0.f, Q=0.f;
    for (int bc=0; bc<64; ++bc){ S += partR[(tid*2)*64 + bc]; Q += partR[(tid*2+1)*64 + bc]; }
    float mu  = S * (1.0f/BATCH);
    float var = Q * (1.0f/BATCH) - mu*mu;
    float a = gr[tid] * rsqrtf(var + EPS);
    aL[tid] = a; cL[tid] = betar[tid] - a*mu;
  }
  __syncthreads();
  const int i4 = blockIdx.x*256 + tid;       // 65536 float4s
  float4 v = *reinterpret_cast<const float4*>(Hr + (size_t)i4*4);
  int o = (i4*4)&63;
  float4 r;
  r.x = aL[o  ]*v.x + cL[o  ];
  r.y = aL[o+1]*v.y + cL[o+1];
  r.z = aL[o+2]*v.z + cL[o+2];
  r.w = aL[o+3]*v.w + cL[o+3];
  *reinterpret_cast<float4*>(out + (size_t)i4*4) = r;
}

extern "C" void kernel_launch(void* const* d_in, const int* in_sizes, int n_in,
                              void* d_out, int out_size, void* d_ws, size_t ws_size,
                              hipStream_t stream) {
  const float* ms    = (const float*)d_in[0];
  const int*   gidx  = (const int*)  d_in[1];
  const float* W1    = (const float*)d_in[2];
  const float* b1    = (const float*)d_in[3];
  const float* g1    = (const float*)d_in[4];
  const float* beta1 = (const float*)d_in[5];
  const float* W2    = (const float*)d_in[6];
  const float* b2    = (const float*)d_in[7];
  const float* g2    = (const float*)d_in[8];
  const float* beta2 = (const float*)d_in[9];
  const float* W3    = (const float*)d_in[10];
  const float* b3    = (const float*)d_in[11];
  const float* g3    = (const float*)d_in[12];
  const float* beta3 = (const float*)d_in[13];
  const float* Wr    = (const float*)d_in[14];
  const float* br    = (const float*)d_in[15];
  const float* gr    = (const float*)d_in[16];
  const float* betar = (const float*)d_in[17];
  float* out = (float*)d_out;

  char* w = (char*)d_ws;
  size_t off = 0;
  auto take = [&](size_t bytes)->char*{
    char* p = w + off;
    off = (off + bytes + 255) & ~(size_t)255;
    return p;
  };
  h16*   msT    = (h16*)  take((size_t)6000*BATCH*2);
  h16*   H2     = (h16*)  take((size_t)64*BATCH*24*2);
  h16*   H3     = (h16*)  take((size_t)BATCH*256*2);
  float* Hr     = (float*)take((size_t)BATCH*64*4);
  float* part1  = (float*)take((size_t)10240*2*16*4);
  float* part2  = (float*)take((size_t)1536*2*64*4);
  float* part3  = (float*)take((size_t)256*2*64*4);
  float* partR  = (float*)take((size_t)64*2*64*4);
  float* W2f    = (float*)take((size_t)64*24*160*4);
  float* b2f    = (float*)take((size_t)64*24*4);
  if (off > ws_size) return;

  k_transpose<<<dim3(94,64), 256, 0, stream>>>(ms, msT);
  k_statsA<<<dim3(16,512), 64, 0, stream>>>(msT, gidx, W1, b1, part1);
  k_fold2<<<64, 256, 0, stream>>>(W2, b2, g1, beta1, part1, W2f, b2f);
  k_passB<<<dim3(64,64), 256, 0, stream>>>(msT, gidx, W1, b1, W2f, b2f, H2, part2);
  k_passC<<<dim3(64,8), 512, 0, stream>>>(H2, part2, g2, beta2, W3, b3, H3, part3);
  k_passD<<<dim3(64,8), 256, 0, stream>>>(H3, part3, g3, beta3, Wr, br, Hr, partR);
  k_final<<<256, 256, 0, stream>>>(Hr, partR, gr, betar, out);
}

// Round 5
// 185.404 us; speedup vs baseline: 1.9364x; 1.9364x over previous
//
#include <hip/hip_runtime.h>
#include <hip/hip_fp16.h>

#define BATCH 4096
#define EPS 1e-5f

typedef __half h16;
typedef float f32x2 __attribute__((ext_vector_type(2)));

union H8 { float4 f4; h16 h[8]; };
union H4 { float2 f2; h16 h[4]; __half2 h2[2]; };
union H2U { float f; __half2 h2; unsigned int u; };

__device__ __forceinline__ float tanh_fast(float x){
  float e = __expf(2.0f*x);
  return 1.0f - 2.0f*__builtin_amdgcn_rcpf(e + 1.0f);
}

__device__ __forceinline__ float wred(float v){
  #pragma unroll
  for (int off=32; off; off>>=1) v += __shfl_xor(v, off);
  return v;
}

// ---------------- transpose: ms[4096][6000] f32 -> msT[6000][4096] f16 ----------------
__global__ __launch_bounds__(256) void k_transpose(const float* __restrict__ ms, h16* __restrict__ msT){
  __shared__ float tile[64][65];
  int tc = blockIdx.x * 64;
  int tb = blockIdx.y * 64;
  int tx = threadIdx.x & 63;
  int ty = threadIdx.x >> 6;
  #pragma unroll
  for (int k=0;k<16;++k){
    int r = ty + k*4;
    int c = tc + tx;
    if (c < 6000) tile[r][tx] = ms[(size_t)(tb + r)*6000 + c];
  }
  __syncthreads();
  #pragma unroll
  for (int k=0;k<16;++k){
    int r = ty + k*4;
    int c = tc + r;
    if (c < 6000) msT[(size_t)c*BATCH + tb + tx] = __float2half(tile[tx][r]);
  }
}

// ---------------- pass A: level-1 linear+tanh -> H1[ch][b] f16 + stats ----------------
// grid (16 bc, 512 s), block 64; thread handles 4 batch elems
__global__ __launch_bounds__(64) void k_statsA(const h16* __restrict__ msT, const int* __restrict__ gidx,
    const float* __restrict__ W1, const float* __restrict__ b1,
    h16* __restrict__ H1, float* __restrict__ part1){
  const int s = blockIdx.y;
  const int bc = blockIdx.x;           // 16
  const int lane = threadIdx.x;
  const int b0 = bc*256 + lane*4;
  const float* Wp = W1 + s*320;
  f32x2 acc[20][2];
  #pragma unroll
  for (int o=0;o<20;++o){
    float bv = b1[s*20+o];
    acc[o][0] = (f32x2){bv,bv};
    acc[o][1] = (f32x2){bv,bv};
  }
  #pragma unroll 4
  for (int g=0; g<16; ++g){
    const int row = gidx[s*16+g]*BATCH;
    H4 u; u.f2 = *reinterpret_cast<const float2*>(msT + row + b0);
    float2 fa = __half22float2(u.h2[0]);
    float2 fb = __half22float2(u.h2[1]);
    f32x2 xa = (f32x2){fa.x, fa.y};
    f32x2 xb = (f32x2){fb.x, fb.y};
    #pragma unroll
    for (int o=0;o<20;++o){
      float wv = Wp[o*16+g];
      f32x2 w2 = (f32x2){wv,wv};
      acc[o][0] = __builtin_elementwise_fma(xa, w2, acc[o][0]);
      acc[o][1] = __builtin_elementwise_fma(xb, w2, acc[o][1]);
    }
  }
  #pragma unroll
  for (int o=0;o<20;++o){
    float h0=tanh_fast(acc[o][0].x), h1=tanh_fast(acc[o][0].y);
    float h2=tanh_fast(acc[o][1].x), h3=tanh_fast(acc[o][1].y);
    H4 u;
    u.h2[0] = __float22half2_rn(make_float2(h0,h1));
    u.h2[1] = __float22half2_rn(make_float2(h2,h3));
    *reinterpret_cast<float2*>(H1 + (size_t)(s*20+o)*BATCH + b0) = u.f2;
    float S = wred((h0+h1)+(h2+h3));
    float Q = wred((h0*h0+h1*h1)+(h2*h2+h3*h3));
    if (lane==0){
      part1[((s*20+o)*2  )*16 + bc] = S;
      part1[((s*20+o)*2+1)*16 + bc] = Q;
    }
  }
}

// ---------------- fold level-1 BN into W2 (transposed [i][j] layout) ----------------
__global__ __launch_bounds__(256) void k_fold2(const float* __restrict__ W, const float* __restrict__ bb,
    const float* __restrict__ g, const float* __restrict__ beta,
    const float* __restrict__ part, float* __restrict__ Wf, float* __restrict__ bf){
  const int p = blockIdx.x;
  const int tid = threadIdx.x;
  __shared__ float aL[160], cL[160];
  for (int t = tid; t < 160; t += 256){
    int ch = p*160 + t;
    float S=0.f, Q=0.f;
    for (int bc=0; bc<16; ++bc){ S += part[(ch*2)*16 + bc]; Q += part[(ch*2+1)*16 + bc]; }
    float mu  = S * (1.0f/BATCH);
    float var = Q * (1.0f/BATCH) - mu*mu;
    float a = g[ch] * rsqrtf(var + EPS);
    aL[t] = a;
    cL[t] = beta[ch] - a*mu;
  }
  __syncthreads();
  const int NW = 160*24;
  for (int e = tid; e < NW; e += 256){
    int j = e % 24, i = e / 24;
    Wf[p*NW + e] = W[p*NW + j*160 + i] * aL[i];
  }
  if (tid < 24){
    float sv = bb[p*24 + tid];
    for (int i=0;i<160;++i) sv = fmaf(W[p*NW + tid*160 + i], cL[i], sv);
    bf[p*24 + tid] = sv;
  }
}

// ---------------- pass B: H1 -> folded level-2 -> H2[p][b][24] + stats ----------------
// grid (16 bc, 64 p), block 256 = 4 waves; waves split over batch (p block-uniform -> scalar weights)
__global__ __launch_bounds__(256) void k_passB(const h16* __restrict__ H1,
    const float* __restrict__ W2f, const float* __restrict__ b2f,
    h16* __restrict__ H2, float* __restrict__ part2){
  const int p = blockIdx.y;
  const int bc = blockIdx.x;           // 16
  const int tid = threadIdx.x;
  const int wv = tid >> 6;
  const int lane = tid & 63;
  const int b = bc*256 + wv*64 + lane;
  const int bcw = bc*4 + wv;           // 64 batch chunks
  f32x2 acc2[12];
  #pragma unroll
  for (int j2=0;j2<12;++j2) acc2[j2] = (f32x2){b2f[p*24+2*j2], b2f[p*24+2*j2+1]};
  const h16* __restrict__ h1p = H1 + (size_t)p*160*BATCH + b;
  const float* __restrict__ w2p = W2f + p*3840;   // [i][j] layout
  #pragma unroll 4
  for (int i=0;i<160;++i){
    float x = __half2float(h1p[(size_t)i*BATCH]);
    f32x2 x2 = (f32x2){x,x};
    #pragma unroll
    for (int j2=0;j2<12;++j2){
      f32x2 w2 = (f32x2){w2p[i*24+2*j2], w2p[i*24+2*j2+1]};
      acc2[j2] = __builtin_elementwise_fma(x2, w2, acc2[j2]);
    }
  }
  float v[24];
  #pragma unroll
  for (int j2=0;j2<12;++j2){
    v[2*j2]   = tanh_fast(acc2[j2].x);
    v[2*j2+1] = tanh_fast(acc2[j2].y);
  }
  {
    h16* dst = H2 + ((size_t)p*BATCH + b)*24;
    H8 u;
    #pragma unroll
    for (int t=0;t<3;++t){
      #pragma unroll
      for (int j=0;j<8;++j) u.h[j] = __float2half(v[t*8+j]);
      *reinterpret_cast<float4*>(dst + t*8) = u.f4;
    }
  }
  #pragma unroll
  for (int j=0;j<24;++j){
    float S = wred(v[j]);
    float Q = wred(v[j]*v[j]);
    if (lane==0){
      part2[((p*24+j)*2  )*64 + bcw] = S;
      part2[((p*24+j)*2+1)*64 + bcw] = Q;
    }
  }
}

// ---------------- pass C: inline-BN(level2) + level-3 -> H3[b][256] + stats ----------------
// grid (64 bc, 8 q), block 512 (8 waves x 4 outputs)
__global__ __launch_bounds__(512) void k_passC(const h16* __restrict__ H2, const float* __restrict__ part2,
    const float* __restrict__ g2, const float* __restrict__ beta2,
    const float* __restrict__ W3, const float* __restrict__ b3,
    h16* __restrict__ H3, float* __restrict__ part3){
  const int q = blockIdx.y;
  const int bc = blockIdx.x;           // 64
  const int tid = threadIdx.x;
  const int wv = tid >> 6;
  const int lane = tid & 63;
  __shared__ float aL[192], cL[192];
  for (int t = tid; t < 192; t += 512){
    int ch = q*192 + t;
    float S=0.f, Q=0.f;
    for (int c=0;c<64;++c){ S += part2[(ch*2)*64 + c]; Q += part2[(ch*2+1)*64 + c]; }
    float mu  = S * (1.0f/BATCH);
    float var = Q * (1.0f/BATCH) - mu*mu;
    float a = g2[ch] * rsqrtf(var + EPS);
    aL[t] = a; cL[t] = beta2[ch] - a*mu;
  }
  __syncthreads();
  const int b = bc*64 + lane;
  const int jb = wv*4;
  float acc[4];
  #pragma unroll
  for (int j=0;j<4;++j) acc[j] = b3[q*32 + jb + j];
  for (int c2=0;c2<8;++c2){
    const h16* src = H2 + ((size_t)(q*8+c2)*BATCH + b)*24;
    float xn[24];
    #pragma unroll
    for (int t=0;t<3;++t){
      H8 u; u.f4 = *reinterpret_cast<const float4*>(src + t*8);
      #pragma unroll
      for (int i=0;i<8;++i){
        int ci = c2*24 + t*8 + i;
        xn[t*8+i] = fmaf(aL[ci], __half2float(u.h[i]), cL[ci]);
      }
    }
    #pragma unroll
    for (int j=0;j<4;++j){
      const float* wr = W3 + q*6144 + (jb+j)*192 + c2*24;
      #pragma unroll
      for (int i=0;i<24;++i) acc[j] = fmaf(xn[i], wr[i], acc[j]);
    }
  }
  #pragma unroll
  for (int j=0;j<4;++j) acc[j] = tanh_fast(acc[j]);
  {
    h16* dst = H3 + (size_t)b*256 + q*32 + jb;
    H2U u0,u1;
    u0.h2 = __halves2half2(__float2half(acc[0]), __float2half(acc[1]));
    u1.h2 = __halves2half2(__float2half(acc[2]), __float2half(acc[3]));
    float2 vv; vv.x = u0.f; vv.y = u1.f;
    *reinterpret_cast<float2*>(dst) = vv;
  }
  #pragma unroll
  for (int j=0;j<4;++j){
    float S = wred(acc[j]);
    float Q = wred(acc[j]*acc[j]);
    if (lane==0){
      part3[((q*32+jb+j)*2  )*64 + bc] = S;
      part3[((q*32+jb+j)*2+1)*64 + bc] = Q;
    }
  }
}

// ---------------- pass D: inline-BN(level3) + root -> Hr f32 [b][64] + stats ----------------
// grid (64 bc, 8 jg), block 256 = 4 waves; wave wv handles channels [wv*64, wv*64+64); LDS combine
__global__ __launch_bounds__(256) void k_passD(const h16* __restrict__ H3, const float* __restrict__ part3,
    const float* __restrict__ g3, const float* __restrict__ beta3,
    const float* __restrict__ Wr, const float* __restrict__ br,
    float* __restrict__ Hr, float* __restrict__ partR){
  const int bc = blockIdx.x;           // 64
  const int jb = blockIdx.y * 8;       // 8 groups
  const int tid = threadIdx.x;
  const int wv = tid >> 6;
  const int lane = tid & 63;
  __shared__ float aL[256], cL[256];
  __shared__ float lacc[4][64][9];
  {
    float S=0.f, Q=0.f;
    for (int c=0;c<64;++c){ S += part3[(tid*2)*64 + c]; Q += part3[(tid*2+1)*64 + c]; }
    float mu  = S * (1.0f/BATCH);
    float var = Q * (1.0f/BATCH) - mu*mu;
    float a = g3[tid] * rsqrtf(var + EPS);
    aL[tid] = a; cL[tid] = beta3[tid] - a*mu;
  }
  __syncthreads();
  const int b = bc*64 + lane;
  float acc[8];
  #pragma unroll
  for (int j=0;j<8;++j) acc[j] = 0.f;
  const h16* src = H3 + (size_t)b*256 + wv*64;
  #pragma unroll
  for (int kk=0; kk<8; ++kk){
    const int sl = wv*8 + kk;
    H8 u; u.f4 = *reinterpret_cast<const float4*>(src + kk*8);
    float xn[8];
    #pragma unroll
    for (int i=0;i<8;++i){
      int ci = sl*8+i;
      xn[i] = fmaf(aL[ci], __half2float(u.h[i]), cL[ci]);
    }
    #pragma unroll
    for (int j=0;j<8;++j){
      const float* wr = Wr + (jb+j)*256 + sl*8;
      #pragma unroll
      for (int i=0;i<8;++i) acc[j] = fmaf(xn[i], wr[i], acc[j]);
    }
  }
  #pragma unroll
  for (int j=0;j<8;++j) lacc[wv][lane][j] = acc[j];
  __syncthreads();
  #pragma unroll
  for (int k=0;k<2;++k){
    const int j = k*4 + wv;
    float v = br[jb+j] + (lacc[0][lane][j] + lacc[1][lane][j]) + (lacc[2][lane][j] + lacc[3][lane][j]);
    v = tanh_fast(v);
    Hr[(size_t)b*64 + jb + j] = v;
    float S = wred(v);
    float Q = wred(v*v);
    if (lane==0){
      partR[((jb+j)*2  )*64 + bc] = S;
      partR[((jb+j)*2+1)*64 + bc] = Q;
    }
  }
}

// ---------------- final BN on root output ----------------
__global__ __launch_bounds__(256) void k_final(const float* __restrict__ Hr, const float* __restrict__ partR,
    const float* __restrict__ gr, const float* __restrict__ betar, float* __restrict__ out){
  __shared__ float aL[64], cL[64];
  const int tid = threadIdx.x;
  if (tid < 64){
    float S=0.f, Q=0.f;
    for (int bc=0; bc<64; ++bc){ S += partR[(tid*2)*64 + bc]; Q += partR[(tid*2+1)*64 + bc]; }
    float mu  = S * (1.0f/BATCH);
    float var = Q * (1.0f/BATCH) - mu*mu;
    float a = gr[tid] * rsqrtf(var + EPS);
    aL[tid] = a; cL[tid] = betar[tid] - a*mu;
  }
  __syncthreads();
  const int i4 = blockIdx.x*256 + tid;       // 65536 float4s
  float4 v = *reinterpret_cast<const float4*>(Hr + (size_t)i4*4);
  int o = (i4*4)&63;
  float4 r;
  r.x = aL[o  ]*v.x + cL[o  ];
  r.y = aL[o+1]*v.y + cL[o+1];
  r.z = aL[o+2]*v.z + cL[o+2];
  r.w = aL[o+3]*v.w + cL[o+3];
  *reinterpret_cast<float4*>(out + (size_t)i4*4) = r;
}

extern "C" void kernel_launch(void* const* d_in, const int* in_sizes, int n_in,
                              void* d_out, int out_size, void* d_ws, size_t ws_size,
                              hipStream_t stream) {
  const float* ms    = (const float*)d_in[0];
  const int*   gidx  = (const int*)  d_in[1];
  const float* W1    = (const float*)d_in[2];
  const float* b1    = (const float*)d_in[3];
  const float* g1    = (const float*)d_in[4];
  const float* beta1 = (const float*)d_in[5];
  const float* W2    = (const float*)d_in[6];
  const float* b2    = (const float*)d_in[7];
  const float* g2    = (const float*)d_in[8];
  const float* beta2 = (const float*)d_in[9];
  const float* W3    = (const float*)d_in[10];
  const float* b3    = (const float*)d_in[11];
  const float* g3    = (const float*)d_in[12];
  const float* beta3 = (const float*)d_in[13];
  const float* Wr    = (const float*)d_in[14];
  const float* br    = (const float*)d_in[15];
  const float* gr    = (const float*)d_in[16];
  const float* betar = (const float*)d_in[17];
  float* out = (float*)d_out;

  char* w = (char*)d_ws;
  size_t off = 0;
  auto take = [&](size_t bytes)->char*{
    char* p = w + off;
    off = (off + bytes + 255) & ~(size_t)255;
    return p;
  };
  h16*   msT    = (h16*)  take((size_t)6000*BATCH*2);
  h16*   H1     = (h16*)  take((size_t)10240*BATCH*2);
  h16*   H2     = (h16*)  take((size_t)64*BATCH*24*2);
  h16*   H3     = (h16*)  take((size_t)BATCH*256*2);
  float* Hr     = (float*)take((size_t)BATCH*64*4);
  float* part1  = (float*)take((size_t)10240*2*16*4);
  float* part2  = (float*)take((size_t)1536*2*64*4);
  float* part3  = (float*)take((size_t)256*2*64*4);
  float* partR  = (float*)take((size_t)64*2*64*4);
  float* W2f    = (float*)take((size_t)64*24*160*4);
  float* b2f    = (float*)take((size_t)64*24*4);
  if (off > ws_size) return;

  k_transpose<<<dim3(94,64), 256, 0, stream>>>(ms, msT);
  k_statsA<<<dim3(16,512), 64, 0, stream>>>(msT, gidx, W1, b1, H1, part1);
  k_fold2<<<64, 256, 0, stream>>>(W2, b2, g1, beta1, part1, W2f, b2f);
  k_passB<<<dim3(16,64), 256, 0, stream>>>(H1, W2f, b2f, H2, part2);
  k_passC<<<dim3(64,8), 512, 0, stream>>>(H2, part2, g2, beta2, W3, b3, H3, part3);
  k_passD<<<dim3(64,8), 256, 0, stream>>>(H3, part3, g3, beta3, Wr, br, Hr, partR);
  k_final<<<256, 256, 0, stream>>>(Hr, partR, gr, betar, out);
}